// Round 1
// baseline (691.538 us; speedup 1.0000x reference)
//
#include <hip/hip_runtime.h>
#include <hip/hip_bf16.h>

typedef long long TLONG;
typedef float  f32x4_t  __attribute__((ext_vector_type(4)));
typedef short  s16x8_t  __attribute__((ext_vector_type(8)));
typedef short  s16x4_t  __attribute__((ext_vector_type(4)));
typedef __bf16 bf16x8_t __attribute__((ext_vector_type(8)));

#define MDIM 32768
#define NDIM 1024
#define KDIM 1024
#define EPSV 1e-6f

__device__ __forceinline__ unsigned short f2bf_bits(float f) {
  __hip_bfloat16 h = __float2bfloat16(f);
  return __builtin_bit_cast(unsigned short, h);
}
__device__ __forceinline__ float bf2f(unsigned short u) {
  unsigned int x = ((unsigned int)u) << 16;
  return __builtin_bit_cast(float, x);
}
// async global->LDS, 16B per lane. LDS dest must be wave-uniform base + lane*16.
__device__ __forceinline__ void load_lds16(const void* g, void* l) {
  __builtin_amdgcn_global_load_lds((const __attribute__((address_space(1))) void*)g,
                                   (__attribute__((address_space(3))) void*)l, 16, 0, 0);
}

// ---------------------------------------------------------------- convert
__global__ __launch_bounds__(256) void convert_f32_bf16(
    const float* __restrict__ in, unsigned short* __restrict__ out, TLONG n) {
  TLONG i = ((TLONG)blockIdx.x * blockDim.x + threadIdx.x) * 8;
  const TLONG stride = (TLONG)gridDim.x * blockDim.x * 8;
  for (; i < n; i += stride) {
    f32x4_t a = *reinterpret_cast<const f32x4_t*>(in + i);
    f32x4_t b = *reinterpret_cast<const f32x4_t*>(in + i + 4);
    s16x8_t o;
    o[0] = (short)f2bf_bits(a[0]); o[1] = (short)f2bf_bits(a[1]);
    o[2] = (short)f2bf_bits(a[2]); o[3] = (short)f2bf_bits(a[3]);
    o[4] = (short)f2bf_bits(b[0]); o[5] = (short)f2bf_bits(b[1]);
    o[6] = (short)f2bf_bits(b[2]); o[7] = (short)f2bf_bits(b[3]);
    *reinterpret_cast<s16x8_t*>(out + i) = o;
  }
}

// ---------------------------------------------------------------- GEMM (m97-style)
// C[m][n] = f(sum_k A[m][k]*W[n][k] + bias[n]); M=32768, N=K=1024.
// 128x128 tile, BK=32, 256 thr (2x2 waves), 16x16x32 bf16 MFMA.
// LDS 16B-slot XOR swizzle (slot ^= (row>>1)&3) applied on BOTH staging source
// and reads -> 2-way-max bank aliasing (free).
template <int FMAP, int OUTF32>
__global__ __launch_bounds__(256) void gemm_bt(
    const unsigned short* __restrict__ A, const unsigned short* __restrict__ W,
    const float* __restrict__ bias, void* __restrict__ Cout) {
  const int bid = blockIdx.x;                     // 2048 blocks
  const int swz = (bid & 7) * 256 + (bid >> 3);   // XCD-chunked swizzle (2048%8==0)
  const int mt = swz >> 3;                        // 0..255
  const int nt = swz & 7;                         // 0..7

  const int tid = threadIdx.x;
  const int lane = tid & 63;
  const int w = tid >> 6;
  const int wr = w >> 1, wc = w & 1;
  const int l15 = lane & 15, lh = lane >> 4;

  __shared__ short sA[128 * 32];
  __shared__ short sB[128 * 32];

  f32x4_t acc[4][4];
#pragma unroll
  for (int m = 0; m < 4; ++m)
#pragma unroll
    for (int n = 0; n < 4; ++n) acc[m][n] = (f32x4_t)0.0f;

  const int arow0 = mt * 128;
  const int brow0 = nt * 128;

  for (int kt = 0; kt < KDIM / 32; ++kt) {
    const int k0 = kt * 32;
#pragma unroll
    for (int i = 0; i < 2; ++i) {                 // stage A: 512 x 16B chunks
      const int c = i * 256 + tid;
      const int r = c >> 2, s = c & 3;
      const int sg = s ^ ((r >> 1) & 3);
      load_lds16(A + ((arow0 + r) * KDIM + k0 + sg * 8), &sA[c * 8]);
    }
#pragma unroll
    for (int i = 0; i < 2; ++i) {                 // stage B
      const int c = i * 256 + tid;
      const int r = c >> 2, s = c & 3;
      const int sg = s ^ ((r >> 1) & 3);
      load_lds16(W + ((brow0 + r) * KDIM + k0 + sg * 8), &sB[c * 8]);
    }
    __syncthreads();
    bf16x8_t a[4], b[4];
#pragma unroll
    for (int m = 0; m < 4; ++m) {
      const int rA = wr * 64 + m * 16 + l15;
      const int sl = lh ^ ((rA >> 1) & 3);
      a[m] = __builtin_bit_cast(bf16x8_t,
          *reinterpret_cast<const s16x8_t*>(&sA[rA * 32 + sl * 8]));
    }
#pragma unroll
    for (int n = 0; n < 4; ++n) {
      const int rB = wc * 64 + n * 16 + l15;
      const int sl = lh ^ ((rB >> 1) & 3);
      b[n] = __builtin_bit_cast(bf16x8_t,
          *reinterpret_cast<const s16x8_t*>(&sB[rB * 32 + sl * 8]));
    }
#pragma unroll
    for (int m = 0; m < 4; ++m)
#pragma unroll
      for (int n = 0; n < 4; ++n)
        acc[m][n] = __builtin_amdgcn_mfma_f32_16x16x32_bf16(a[m], b[n], acc[m][n], 0, 0, 0);
    __syncthreads();
  }

  // epilogue: C/D layout col = lane&15, row = (lane>>4)*4 + j  [m89/m91]
#pragma unroll
  for (int n = 0; n < 4; ++n) {
    const int col = nt * 128 + wc * 64 + n * 16 + l15;
    const float bv = bias[col];
#pragma unroll
    for (int m = 0; m < 4; ++m) {
      const int row0 = mt * 128 + wr * 64 + m * 16 + lh * 4;
#pragma unroll
      for (int j = 0; j < 4; ++j) {
        float v = acc[m][n][j] + bv;
        if (FMAP) v = (v > 0.0f) ? (v + 1.0f) : __expf(v);  // elu(x)+1
        if (OUTF32)
          reinterpret_cast<float*>(Cout)[(row0 + j) * NDIM + col] = v;
        else
          reinterpret_cast<unsigned short*>(Cout)[(row0 + j) * NDIM + col] = f2bf_bits(v);
      }
    }
  }
}

// ---------------------------------------------------------------- kv + k_sum
// kvT[bh][e][d] = sum_t k[b,t,h,d]*v[b,t,h,e];  ksum[bh][d] = sum_t k.
// 512 blocks = 64 bh x 8 t-chunks (1024 rows each); fp32 atomic reduce.
__global__ __launch_bounds__(256) void kv_ksum_kernel(
    const unsigned short* __restrict__ kf, const unsigned short* __restrict__ vf,
    float* __restrict__ kvT, float* __restrict__ ksum) {
  const int bid = blockIdx.x;
  const int bh = bid >> 3, ch = bid & 7;
  const int b = bh >> 4, h = bh & 15;
  const int tid = threadIdx.x;
  const int dg = tid >> 4, eg = tid & 15;   // thread owns 4x4 (d,e) sub-block
  __shared__ short sk[64 * 64];
  __shared__ short sv[64 * 64];
  float acc[4][4] = {};
  float ks[4] = {0.f, 0.f, 0.f, 0.f};
  const int rowbase = (b * 8192 + ch * 1024) * 1024 + h * 64;
  for (int tt = 0; tt < 1024; tt += 64) {
#pragma unroll
    for (int i = 0; i < 2; ++i) {
      const int c = i * 256 + tid;
      const int r = c >> 3, s = c & 7;
      load_lds16(kf + rowbase + (tt + r) * 1024 + s * 8, &sk[c * 8]);
      load_lds16(vf + rowbase + (tt + r) * 1024 + s * 8, &sv[c * 8]);
    }
    __syncthreads();
    for (int tl = 0; tl < 64; ++tl) {
      s16x4_t kr = *reinterpret_cast<const s16x4_t*>(&sk[tl * 64 + dg * 4]);
      s16x4_t vr = *reinterpret_cast<const s16x4_t*>(&sv[tl * 64 + eg * 4]);
      float kv4[4], vv4[4];
#pragma unroll
      for (int i = 0; i < 4; ++i) {
        kv4[i] = bf2f((unsigned short)kr[i]);
        vv4[i] = bf2f((unsigned short)vr[i]);
      }
#pragma unroll
      for (int i = 0; i < 4; ++i)
#pragma unroll
        for (int j = 0; j < 4; ++j) acc[i][j] += kv4[i] * vv4[j];
      if (eg == 0) {
#pragma unroll
        for (int i = 0; i < 4; ++i) ks[i] += kv4[i];
      }
    }
    __syncthreads();
  }
#pragma unroll
  for (int i = 0; i < 4; ++i) {
    if (eg == 0) atomicAdd(&ksum[bh * 64 + dg * 4 + i], ks[i]);
#pragma unroll
    for (int j = 0; j < 4; ++j)
      atomicAdd(&kvT[(bh * 64 + eg * 4 + j) * 64 + dg * 4 + i], acc[i][j]);
  }
}

// ---------------------------------------------------------------- out = q@kv / (q.ksum+eps)
// Per bh: (8192x64)@(64x64). A-frags straight from global q (L1/L2 reuse),
// B-frags from L2-resident kvT (row e, contiguous d). denom via 16-d partials
// + shfl_xor reduce + shfl redistribute to C-frag rows.
__global__ __launch_bounds__(256) void attn_apply_kernel(
    const unsigned short* __restrict__ qf, const float* __restrict__ kvT,
    const float* __restrict__ ksum, unsigned short* __restrict__ att) {
  const int bid = blockIdx.x;                     // 2048
  const int swz = (bid & 7) * 256 + (bid >> 3);
  const int bh = swz >> 5;
  const int tile = swz & 31;
  const int b = bh >> 4, h = bh & 15;
  const int tid = threadIdx.x;
  const int lane = tid & 63, w = tid >> 6;
  const int l15 = lane & 15, lh = lane >> 4;

  float ksr[16];
#pragma unroll
  for (int i = 0; i < 16; ++i) ksr[i] = ksum[bh * 64 + lh * 16 + i];

  bf16x8_t bfrag[2][4];
#pragma unroll
  for (int ks2 = 0; ks2 < 2; ++ks2)
#pragma unroll
    for (int n = 0; n < 4; ++n) {
      const float* p = kvT + (bh * 64 + n * 16 + l15) * 64 + ks2 * 32 + lh * 8;
      f32x4_t p0 = *reinterpret_cast<const f32x4_t*>(p);
      f32x4_t p1 = *reinterpret_cast<const f32x4_t*>(p + 4);
      s16x8_t t;
      t[0] = (short)f2bf_bits(p0[0]); t[1] = (short)f2bf_bits(p0[1]);
      t[2] = (short)f2bf_bits(p0[2]); t[3] = (short)f2bf_bits(p0[3]);
      t[4] = (short)f2bf_bits(p1[0]); t[5] = (short)f2bf_bits(p1[1]);
      t[6] = (short)f2bf_bits(p1[2]); t[7] = (short)f2bf_bits(p1[3]);
      bfrag[ks2][n] = __builtin_bit_cast(bf16x8_t, t);
    }

  const int rbase = b * 8192 + tile * 256 + w * 64;
  f32x4_t acc[4][4];
#pragma unroll
  for (int m = 0; m < 4; ++m)
#pragma unroll
    for (int n = 0; n < 4; ++n) acc[m][n] = (f32x4_t)0.0f;
  float rden[4][4];

#pragma unroll
  for (int m = 0; m < 4; ++m) {
    const int row = rbase + m * 16 + l15;
    const unsigned short* qrow = qf + row * 1024 + h * 64;
    bf16x8_t afr[2];
#pragma unroll
    for (int ks2 = 0; ks2 < 2; ++ks2)
      afr[ks2] = __builtin_bit_cast(bf16x8_t,
          *reinterpret_cast<const s16x8_t*>(qrow + ks2 * 32 + lh * 8));
    // denom partial over d = lh*16 .. +15 for row (m*16 + l15)
    s16x8_t qa = *reinterpret_cast<const s16x8_t*>(qrow + lh * 16);
    s16x8_t qb = *reinterpret_cast<const s16x8_t*>(qrow + lh * 16 + 8);
    float part = 0.f;
#pragma unroll
    for (int i = 0; i < 8; ++i) part += bf2f((unsigned short)qa[i]) * ksr[i];
#pragma unroll
    for (int i = 0; i < 8; ++i) part += bf2f((unsigned short)qb[i]) * ksr[8 + i];
    part += __shfl_xor(part, 16);
    part += __shfl_xor(part, 32);   // lane now holds denom of row m*16+(lane&15)
#pragma unroll
    for (int j = 0; j < 4; ++j) {
      float dj = __shfl(part, lh * 4 + j);   // denom for C-frag row lh*4+j
      rden[m][j] = 1.0f / (dj + EPSV);
    }
#pragma unroll
    for (int ks2 = 0; ks2 < 2; ++ks2)
#pragma unroll
      for (int n = 0; n < 4; ++n)
        acc[m][n] = __builtin_amdgcn_mfma_f32_16x16x32_bf16(afr[ks2], bfrag[ks2][n], acc[m][n], 0, 0, 0);
  }

#pragma unroll
  for (int m = 0; m < 4; ++m)
#pragma unroll
    for (int n = 0; n < 4; ++n) {
      const int col = h * 64 + n * 16 + l15;
#pragma unroll
      for (int j = 0; j < 4; ++j) {
        const int row = rbase + m * 16 + lh * 4 + j;
        att[row * 1024 + col] = f2bf_bits(acc[m][n][j] * rden[m][j]);
      }
    }
}

// ---------------------------------------------------------------- launch
extern "C" void kernel_launch(void* const* d_in, const int* in_sizes, int n_in,
                              void* d_out, int out_size, void* d_ws, size_t ws_size,
                              hipStream_t stream) {
  const float* query = (const float*)d_in[0];
  const float* key   = (const float*)d_in[1];
  const float* value = (const float*)d_in[2];
  const float* Wq = (const float*)d_in[3];
  const float* bq = (const float*)d_in[4];
  const float* Wk = (const float*)d_in[5];
  const float* bk = (const float*)d_in[6];
  const float* Wv = (const float*)d_in[7];
  const float* bv = (const float*)d_in[8];
  const float* Wo = (const float*)d_in[9];
  const float* bo = (const float*)d_in[10];
  float* out = (float*)d_out;

  // ws layout (bytes):
  //   0         Vbf   (33.5M bf16)
  //   64M       qf
  //   128M      kf
  //   192M      vf  (reused as att after kv_ksum)
  //   256M      Wq/Wk/Wv/Wo bf16 (4 x 2MB)
  //   264M      kvT f32 (64*64*64) then ksum f32 (64*64), contiguous
  if (ws_size < 277889024ULL) return;   // fail cleanly if scratch too small
  char* ws = (char*)d_ws;
  unsigned short* Vbf = (unsigned short*)(ws + 0);
  unsigned short* qf  = (unsigned short*)(ws + 67108864);
  unsigned short* kf  = (unsigned short*)(ws + 134217728);
  unsigned short* vf  = (unsigned short*)(ws + 201326592);  // also att
  unsigned short* Wqb = (unsigned short*)(ws + 268435456);
  unsigned short* Wkb = Wqb + 1048576;
  unsigned short* Wvb = Wkb + 1048576;
  unsigned short* Wob = Wvb + 1048576;
  float* kvT  = (float*)(ws + 276824064);
  // ksum lives right after kvT (one memset covers both)

  // d_out (134MB f32) doubles as bf16 scratch for query/key until final GEMM
  unsigned short* Qbf = (unsigned short*)d_out;
  unsigned short* Kbf = Qbf + 33554432;

  hipMemsetAsync(kvT, 0, (size_t)(64 * 64 * 64 + 64 * 64) * sizeof(float), stream);

  convert_f32_bf16<<<2048, 256, 0, stream>>>(query, Qbf, 33554432LL);
  convert_f32_bf16<<<2048, 256, 0, stream>>>(key,   Kbf, 33554432LL);
  convert_f32_bf16<<<2048, 256, 0, stream>>>(value, Vbf, 33554432LL);
  convert_f32_bf16<<<512, 256, 0, stream>>>(Wq, Wqb, 1048576LL);
  convert_f32_bf16<<<512, 256, 0, stream>>>(Wk, Wkb, 1048576LL);
  convert_f32_bf16<<<512, 256, 0, stream>>>(Wv, Wvb, 1048576LL);
  convert_f32_bf16<<<512, 256, 0, stream>>>(Wo, Wob, 1048576LL);

  gemm_bt<1, 0><<<2048, 256, 0, stream>>>(Qbf, Wqb, bq, qf);   // q = fmap(query@Wq^T)
  gemm_bt<1, 0><<<2048, 256, 0, stream>>>(Kbf, Wkb, bk, kf);   // k = fmap(key@Wk^T)
  gemm_bt<0, 0><<<2048, 256, 0, stream>>>(Vbf, Wvb, bv, vf);   // v = value@Wv^T

  kv_ksum_kernel<<<512, 256, 0, stream>>>(kf, vf, kvT, (float*)(ws + 277872640));

  attn_apply_kernel<<<2048, 256, 0, stream>>>(qf, kvT, (float*)(ws + 277872640), vf);

  gemm_bt<0, 1><<<2048, 256, 0, stream>>>(vf, Wob, bo, out);   // final: att@Wo^T -> f32
}

// Round 2
// 674.313 us; speedup vs baseline: 1.0255x; 1.0255x over previous
//
#include <hip/hip_runtime.h>
#include <hip/hip_bf16.h>

typedef long long TLONG;
typedef float  f32x4_t  __attribute__((ext_vector_type(4)));
typedef short  s16x8_t  __attribute__((ext_vector_type(8)));
typedef short  s16x4_t  __attribute__((ext_vector_type(4)));
typedef __bf16 bf16x8_t __attribute__((ext_vector_type(8)));

#define MDIM 32768
#define NDIM 1024
#define KDIM 1024
#define EPSV 1e-6f

__device__ __forceinline__ unsigned short f2bf_bits(float f) {
  __hip_bfloat16 h = __float2bfloat16(f);
  return __builtin_bit_cast(unsigned short, h);
}
__device__ __forceinline__ float bf2f(unsigned short u) {
  unsigned int x = ((unsigned int)u) << 16;
  return __builtin_bit_cast(float, x);
}
// async global->LDS, 16B per lane. LDS dest must be wave-uniform base + lane*16.
__device__ __forceinline__ void load_lds16(const void* g, void* l) {
  __builtin_amdgcn_global_load_lds((const __attribute__((address_space(1))) void*)g,
                                   (__attribute__((address_space(3))) void*)l, 16, 0, 0);
}

// ---------------------------------------------------------------- convert
__global__ __launch_bounds__(256) void convert_f32_bf16(
    const float* __restrict__ in, unsigned short* __restrict__ out, TLONG n) {
  TLONG i = ((TLONG)blockIdx.x * blockDim.x + threadIdx.x) * 8;
  const TLONG stride = (TLONG)gridDim.x * blockDim.x * 8;
  for (; i < n; i += stride) {
    f32x4_t a = *reinterpret_cast<const f32x4_t*>(in + i);
    f32x4_t b = *reinterpret_cast<const f32x4_t*>(in + i + 4);
    s16x8_t o;
    o[0] = (short)f2bf_bits(a[0]); o[1] = (short)f2bf_bits(a[1]);
    o[2] = (short)f2bf_bits(a[2]); o[3] = (short)f2bf_bits(a[3]);
    o[4] = (short)f2bf_bits(b[0]); o[5] = (short)f2bf_bits(b[1]);
    o[6] = (short)f2bf_bits(b[2]); o[7] = (short)f2bf_bits(b[3]);
    *reinterpret_cast<s16x8_t*>(out + i) = o;
  }
}

// ---------------------------------------------------------------- GEMM (m97-style)
// C[m][n] = f(sum_k A[m][k]*W[n][k] + bias[n]); M=32768, N=K=1024.
// 128x128 tile, BK=32, 256 thr (2x2 waves), 16x16x32 bf16 MFMA.
// OUT: 0 = bf16 row-major [m][n]; 1 = f32 row-major; 2 = bf16 transposed to
//      [b][h][d][t] (b=m>>13, t=m&8191, h=n>>6, d=n&63) — packed ushort4 along t.
template <int FMAP, int OUT>
__global__ __launch_bounds__(256) void gemm_bt(
    const unsigned short* __restrict__ A, const unsigned short* __restrict__ W,
    const float* __restrict__ bias, void* __restrict__ Cout) {
  const int bid = blockIdx.x;                     // 2048 blocks
  const int swz = (bid & 7) * 256 + (bid >> 3);   // XCD-chunked swizzle (2048%8==0)
  const int mt = swz >> 3;                        // 0..255
  const int nt = swz & 7;                         // 0..7

  const int tid = threadIdx.x;
  const int lane = tid & 63;
  const int w = tid >> 6;
  const int wr = w >> 1, wc = w & 1;
  const int l15 = lane & 15, lh = lane >> 4;

  __shared__ short sA[128 * 32];
  __shared__ short sB[128 * 32];

  f32x4_t acc[4][4];
#pragma unroll
  for (int m = 0; m < 4; ++m)
#pragma unroll
    for (int n = 0; n < 4; ++n) acc[m][n] = (f32x4_t)0.0f;

  const int arow0 = mt * 128;
  const int brow0 = nt * 128;

  for (int kt = 0; kt < KDIM / 32; ++kt) {
    const int k0 = kt * 32;
#pragma unroll
    for (int i = 0; i < 2; ++i) {                 // stage A: 512 x 16B chunks
      const int c = i * 256 + tid;
      const int r = c >> 2, s = c & 3;
      const int sg = s ^ ((r >> 1) & 3);
      load_lds16(A + ((arow0 + r) * KDIM + k0 + sg * 8), &sA[c * 8]);
    }
#pragma unroll
    for (int i = 0; i < 2; ++i) {                 // stage B
      const int c = i * 256 + tid;
      const int r = c >> 2, s = c & 3;
      const int sg = s ^ ((r >> 1) & 3);
      load_lds16(W + ((brow0 + r) * KDIM + k0 + sg * 8), &sB[c * 8]);
    }
    __syncthreads();
    bf16x8_t a[4], b[4];
#pragma unroll
    for (int m = 0; m < 4; ++m) {
      const int rA = wr * 64 + m * 16 + l15;
      const int sl = lh ^ ((rA >> 1) & 3);
      a[m] = __builtin_bit_cast(bf16x8_t,
          *reinterpret_cast<const s16x8_t*>(&sA[rA * 32 + sl * 8]));
    }
#pragma unroll
    for (int n = 0; n < 4; ++n) {
      const int rB = wc * 64 + n * 16 + l15;
      const int sl = lh ^ ((rB >> 1) & 3);
      b[n] = __builtin_bit_cast(bf16x8_t,
          *reinterpret_cast<const s16x8_t*>(&sB[rB * 32 + sl * 8]));
    }
#pragma unroll
    for (int m = 0; m < 4; ++m)
#pragma unroll
      for (int n = 0; n < 4; ++n)
        acc[m][n] = __builtin_amdgcn_mfma_f32_16x16x32_bf16(a[m], b[n], acc[m][n], 0, 0, 0);
    __syncthreads();
  }

  // epilogue: C/D layout col = lane&15, row = (lane>>4)*4 + j  [m89/m91]
#pragma unroll
  for (int n = 0; n < 4; ++n) {
    const int col = nt * 128 + wc * 64 + n * 16 + l15;
    const float bv = bias[col];
#pragma unroll
    for (int m = 0; m < 4; ++m) {
      const int row0 = mt * 128 + wr * 64 + m * 16 + lh * 4;
      if (OUT == 2) {
        // transposed: rows (t) are consecutive for j=0..3 -> pack 8B store
        const int b = row0 >> 13, tl = row0 & 8191;
        const int h = col >> 6, d = col & 63;
        s16x4_t o;
#pragma unroll
        for (int j = 0; j < 4; ++j) {
          float v = acc[m][n][j] + bv;
          if (FMAP) v = (v > 0.0f) ? (v + 1.0f) : __expf(v);
          o[j] = (short)f2bf_bits(v);
        }
        *reinterpret_cast<s16x4_t*>(
            reinterpret_cast<unsigned short*>(Cout) +
            (((b * 16 + h) * 64 + d) * 8192 + tl)) = o;
      } else {
#pragma unroll
        for (int j = 0; j < 4; ++j) {
          float v = acc[m][n][j] + bv;
          if (FMAP) v = (v > 0.0f) ? (v + 1.0f) : __expf(v);  // elu(x)+1
          if (OUT == 1)
            reinterpret_cast<float*>(Cout)[(row0 + j) * NDIM + col] = v;
          else
            reinterpret_cast<unsigned short*>(Cout)[(row0 + j) * NDIM + col] = f2bf_bits(v);
        }
      }
    }
  }
}

// ---------------------------------------------------------------- kv + k_sum (MFMA, streaming)
// Inputs transposed: kT[bh][d][8192 t], vT[bh][e][8192 t] (bf16).
// kvT[bh][e][d] += sum_t vT[e][t]*kT[d][t]; ksum[bh][d] += sum_t kT[d][t].
// 1024 blocks = 64 bh x 16 t-chunks (512 t). 4 waves: w -> (dblk=(w>>1)*32,
// eblk=(w&1)*32), each wave owns 32x32 output = 2x2 MFMA frags. No LDS:
// frag loads are 16B/lane, lh-groups contiguous 64B per row -> coalesced.
__global__ __launch_bounds__(256) void kv_ksum_mfma(
    const unsigned short* __restrict__ kT, const unsigned short* __restrict__ vT,
    float* __restrict__ kvT, float* __restrict__ ksum) {
  const int bid = blockIdx.x;
  const int bh = bid >> 4, ch = bid & 15;
  const int tid = threadIdx.x;
  const int lane = tid & 63, w = tid >> 6;
  const int l15 = lane & 15, lh = lane >> 4;
  const int dblk = (w >> 1) * 32, eblk = (w & 1) * 32;

  f32x4_t acc[2][2];
#pragma unroll
  for (int m = 0; m < 2; ++m)
#pragma unroll
    for (int n = 0; n < 2; ++n) acc[m][n] = (f32x4_t)0.0f;
  float ks0 = 0.f, ks1 = 0.f;

  const int tbase = ch * 512 + lh * 8;
  const unsigned short* ka = kT + (bh * 64 + dblk + l15) * 8192 + tbase;
  const unsigned short* va = vT + (bh * 64 + eblk + l15) * 8192 + tbase;

  for (int t0 = 0; t0 < 512; t0 += 32) {
    s16x8_t ar[2], br[2];
#pragma unroll
    for (int m = 0; m < 2; ++m)
      ar[m] = *reinterpret_cast<const s16x8_t*>(ka + m * 16 * 8192 + t0);
#pragma unroll
    for (int n = 0; n < 2; ++n)
      br[n] = *reinterpret_cast<const s16x8_t*>(va + n * 16 * 8192 + t0);
#pragma unroll
    for (int m = 0; m < 2; ++m)
#pragma unroll
      for (int n = 0; n < 2; ++n)
        acc[m][n] = __builtin_amdgcn_mfma_f32_16x16x32_bf16(
            __builtin_bit_cast(bf16x8_t, ar[m]),
            __builtin_bit_cast(bf16x8_t, br[n]), acc[m][n], 0, 0, 0);
    if (eblk == 0) {
#pragma unroll
      for (int i = 0; i < 8; ++i) ks0 += bf2f((unsigned short)ar[0][i]);
#pragma unroll
      for (int i = 0; i < 8; ++i) ks1 += bf2f((unsigned short)ar[1][i]);
    }
  }

  if (eblk == 0) {  // reduce ksum over lh groups (t-subchunks) and accumulate
    ks0 += __shfl_xor(ks0, 16); ks0 += __shfl_xor(ks0, 32);
    ks1 += __shfl_xor(ks1, 16); ks1 += __shfl_xor(ks1, 32);
    if (lh == 0) {
      atomicAdd(&ksum[bh * 64 + dblk + l15], ks0);
      atomicAdd(&ksum[bh * 64 + dblk + 16 + l15], ks1);
    }
  }
  // D layout: col(l15) = e-frag col, row(lh*4+j) = d-frag row
#pragma unroll
  for (int n = 0; n < 2; ++n) {
    const int e = eblk + n * 16 + l15;
#pragma unroll
    for (int m = 0; m < 2; ++m) {
      const int d0 = dblk + m * 16 + lh * 4;
#pragma unroll
      for (int j = 0; j < 4; ++j)
        atomicAdd(&kvT[(bh * 64 + e) * 64 + d0 + j], acc[m][n][j]);
    }
  }
}

// ---------------------------------------------------------------- out = q@kv / (q.ksum+eps)
// Per bh: (8192x64)@(64x64). A-frags straight from global q (L1/L2 reuse),
// B-frags from L2-resident kvT (row e, contiguous d). denom via 16-d partials
// + shfl_xor reduce + shfl redistribute to C-frag rows.
__global__ __launch_bounds__(256) void attn_apply_kernel(
    const unsigned short* __restrict__ qf, const float* __restrict__ kvT,
    const float* __restrict__ ksum, unsigned short* __restrict__ att) {
  const int bid = blockIdx.x;                     // 2048
  const int swz = (bid & 7) * 256 + (bid >> 3);
  const int bh = swz >> 5;
  const int tile = swz & 31;
  const int b = bh >> 4, h = bh & 15;
  const int tid = threadIdx.x;
  const int lane = tid & 63, w = tid >> 6;
  const int l15 = lane & 15, lh = lane >> 4;

  float ksr[16];
#pragma unroll
  for (int i = 0; i < 16; ++i) ksr[i] = ksum[bh * 64 + lh * 16 + i];

  bf16x8_t bfrag[2][4];
#pragma unroll
  for (int ks2 = 0; ks2 < 2; ++ks2)
#pragma unroll
    for (int n = 0; n < 4; ++n) {
      const float* p = kvT + (bh * 64 + n * 16 + l15) * 64 + ks2 * 32 + lh * 8;
      f32x4_t p0 = *reinterpret_cast<const f32x4_t*>(p);
      f32x4_t p1 = *reinterpret_cast<const f32x4_t*>(p + 4);
      s16x8_t t;
      t[0] = (short)f2bf_bits(p0[0]); t[1] = (short)f2bf_bits(p0[1]);
      t[2] = (short)f2bf_bits(p0[2]); t[3] = (short)f2bf_bits(p0[3]);
      t[4] = (short)f2bf_bits(p1[0]); t[5] = (short)f2bf_bits(p1[1]);
      t[6] = (short)f2bf_bits(p1[2]); t[7] = (short)f2bf_bits(p1[3]);
      bfrag[ks2][n] = __builtin_bit_cast(bf16x8_t, t);
    }

  const int rbase = b * 8192 + tile * 256 + w * 64;
  f32x4_t acc[4][4];
#pragma unroll
  for (int m = 0; m < 4; ++m)
#pragma unroll
    for (int n = 0; n < 4; ++n) acc[m][n] = (f32x4_t)0.0f;
  float rden[4][4];

#pragma unroll
  for (int m = 0; m < 4; ++m) {
    const int row = rbase + m * 16 + l15;
    const unsigned short* qrow = qf + row * 1024 + h * 64;
    bf16x8_t afr[2];
#pragma unroll
    for (int ks2 = 0; ks2 < 2; ++ks2)
      afr[ks2] = __builtin_bit_cast(bf16x8_t,
          *reinterpret_cast<const s16x8_t*>(qrow + ks2 * 32 + lh * 8));
    // denom partial over d = lh*16 .. +15 for row (m*16 + l15)
    s16x8_t qa = *reinterpret_cast<const s16x8_t*>(qrow + lh * 16);
    s16x8_t qb = *reinterpret_cast<const s16x8_t*>(qrow + lh * 16 + 8);
    float part = 0.f;
#pragma unroll
    for (int i = 0; i < 8; ++i) part += bf2f((unsigned short)qa[i]) * ksr[i];
#pragma unroll
    for (int i = 0; i < 8; ++i) part += bf2f((unsigned short)qb[i]) * ksr[8 + i];
    part += __shfl_xor(part, 16);
    part += __shfl_xor(part, 32);   // lane now holds denom of row m*16+(lane&15)
#pragma unroll
    for (int j = 0; j < 4; ++j) {
      float dj = __shfl(part, lh * 4 + j);   // denom for C-frag row lh*4+j
      rden[m][j] = 1.0f / (dj + EPSV);
    }
#pragma unroll
    for (int ks2 = 0; ks2 < 2; ++ks2)
#pragma unroll
      for (int n = 0; n < 4; ++n)
        acc[m][n] = __builtin_amdgcn_mfma_f32_16x16x32_bf16(afr[ks2], bfrag[ks2][n], acc[m][n], 0, 0, 0);
  }

#pragma unroll
  for (int m = 0; m < 4; ++m)
#pragma unroll
    for (int n = 0; n < 4; ++n) {
      const int col = h * 64 + n * 16 + l15;
#pragma unroll
      for (int j = 0; j < 4; ++j) {
        const int row = rbase + m * 16 + lh * 4 + j;
        att[row * 1024 + col] = f2bf_bits(acc[m][n][j] * rden[m][j]);
      }
    }
}

// ---------------------------------------------------------------- launch
extern "C" void kernel_launch(void* const* d_in, const int* in_sizes, int n_in,
                              void* d_out, int out_size, void* d_ws, size_t ws_size,
                              hipStream_t stream) {
  const float* query = (const float*)d_in[0];
  const float* key   = (const float*)d_in[1];
  const float* value = (const float*)d_in[2];
  const float* Wq = (const float*)d_in[3];
  const float* bq = (const float*)d_in[4];
  const float* Wk = (const float*)d_in[5];
  const float* bk = (const float*)d_in[6];
  const float* Wv = (const float*)d_in[7];
  const float* bv = (const float*)d_in[8];
  const float* Wo = (const float*)d_in[9];
  const float* bo = (const float*)d_in[10];
  float* out = (float*)d_out;

  // ws layout (bytes):
  //   0         Vbf   (33.5M bf16)
  //   64M       qf
  //   128M      kTf (transposed [b][h][d][t]) ; later reused? no
  //   192M      vTf (transposed) -> after kv/attn, att lives in Vbf? no: att -> vTf region? must be row-major
  //   256M      Wq/Wk/Wv/Wo bf16 (4 x 2MB)
  //   264M      kvT f32 + ksum f32
  if (ws_size < 277889024ULL) return;   // fail cleanly if scratch too small
  char* ws = (char*)d_ws;
  unsigned short* Vbf = (unsigned short*)(ws + 0);          // value bf16; reused as att (row-major)
  unsigned short* qf  = (unsigned short*)(ws + 67108864);
  unsigned short* kTf = (unsigned short*)(ws + 134217728);  // k transposed
  unsigned short* vTf = (unsigned short*)(ws + 201326592);  // v transposed
  unsigned short* Wqb = (unsigned short*)(ws + 268435456);
  unsigned short* Wkb = Wqb + 1048576;
  unsigned short* Wvb = Wkb + 1048576;
  unsigned short* Wob = Wvb + 1048576;
  float* kvT  = (float*)(ws + 276824064);
  float* ksum = (float*)(ws + 277872640);

  // d_out (134MB f32) doubles as bf16 scratch for query/key until final GEMM
  unsigned short* Qbf = (unsigned short*)d_out;
  unsigned short* Kbf = Qbf + 33554432;

  hipMemsetAsync(kvT, 0, (size_t)(64 * 64 * 64 + 64 * 64) * sizeof(float), stream);

  convert_f32_bf16<<<2048, 256, 0, stream>>>(query, Qbf, 33554432LL);
  convert_f32_bf16<<<2048, 256, 0, stream>>>(key,   Kbf, 33554432LL);
  convert_f32_bf16<<<2048, 256, 0, stream>>>(value, Vbf, 33554432LL);
  convert_f32_bf16<<<512, 256, 0, stream>>>(Wq, Wqb, 1048576LL);
  convert_f32_bf16<<<512, 256, 0, stream>>>(Wk, Wkb, 1048576LL);
  convert_f32_bf16<<<512, 256, 0, stream>>>(Wv, Wvb, 1048576LL);
  convert_f32_bf16<<<512, 256, 0, stream>>>(Wo, Wob, 1048576LL);

  gemm_bt<1, 0><<<2048, 256, 0, stream>>>(Qbf, Wqb, bq, qf);   // q = fmap(query@Wq^T), row-major
  gemm_bt<1, 2><<<2048, 256, 0, stream>>>(Kbf, Wkb, bk, kTf);  // k = fmap(key@Wk^T), transposed
  gemm_bt<0, 2><<<2048, 256, 0, stream>>>(Vbf, Wvb, bv, vTf);  // v = value@Wv^T, transposed

  kv_ksum_mfma<<<1024, 256, 0, stream>>>(kTf, vTf, kvT, ksum);

  attn_apply_kernel<<<2048, 256, 0, stream>>>(qf, kvT, ksum, Vbf);  // att -> Vbf (row-major)

  gemm_bt<0, 1><<<2048, 256, 0, stream>>>(Vbf, Wob, bo, out);  // final: att@Wo^T -> f32
}

// Round 3
// 649.409 us; speedup vs baseline: 1.0649x; 1.0383x over previous
//
#include <hip/hip_runtime.h>
#include <hip/hip_bf16.h>

typedef long long TLONG;
typedef float  f32x4_t  __attribute__((ext_vector_type(4)));
typedef short  s16x8_t  __attribute__((ext_vector_type(8)));
typedef short  s16x4_t  __attribute__((ext_vector_type(4)));
typedef __bf16 bf16x8_t __attribute__((ext_vector_type(8)));

#define MDIM 32768
#define NDIM 1024
#define KDIM 1024
#define EPSV 1e-6f

__device__ __forceinline__ unsigned short f2bf_bits(float f) {
  __hip_bfloat16 h = __float2bfloat16(f);
  return __builtin_bit_cast(unsigned short, h);
}
__device__ __forceinline__ float bf2f(unsigned short u) {
  unsigned int x = ((unsigned int)u) << 16;
  return __builtin_bit_cast(float, x);
}
// async global->LDS, 16B per lane. LDS dest must be wave-uniform base + lane*16.
__device__ __forceinline__ void load_lds16(const void* g, void* l) {
  __builtin_amdgcn_global_load_lds((const __attribute__((address_space(1))) void*)g,
                                   (__attribute__((address_space(3))) void*)l, 16, 0, 0);
}

// ---------------------------------------------------------------- convert
__global__ __launch_bounds__(256) void convert_f32_bf16(
    const float* __restrict__ in, unsigned short* __restrict__ out, TLONG n) {
  TLONG i = ((TLONG)blockIdx.x * blockDim.x + threadIdx.x) * 8;
  const TLONG stride = (TLONG)gridDim.x * blockDim.x * 8;
  for (; i < n; i += stride) {
    f32x4_t a = *reinterpret_cast<const f32x4_t*>(in + i);
    f32x4_t b = *reinterpret_cast<const f32x4_t*>(in + i + 4);
    s16x8_t o;
    o[0] = (short)f2bf_bits(a[0]); o[1] = (short)f2bf_bits(a[1]);
    o[2] = (short)f2bf_bits(a[2]); o[3] = (short)f2bf_bits(a[3]);
    o[4] = (short)f2bf_bits(b[0]); o[5] = (short)f2bf_bits(b[1]);
    o[6] = (short)f2bf_bits(b[2]); o[7] = (short)f2bf_bits(b[3]);
    *reinterpret_cast<s16x8_t*>(out + i) = o;
  }
}

// ---------------------------------------------------------------- GEMM 256x256 deep-pipelined
// C[m][n] = f(sum_k A[m][k]*W[n][k] + bias[n]); M=32768, N=K=1024.
// BM=BN=256, BK=64. 512 thr = 8 waves (2 M x 4 N); wave tile 128x64 = 8x4 frags.
// LDS: 2 K-tile double-buffer, A+B each 256x64 bf16 -> 128 KiB total.
// Swizzle: 16B slot ^= (row&7); linear gload_lds dest + inverse-swz source + swz read.
// Schedule per K-tile kt (buf p=kt&1):
//   reads a0(8)+B(8) | q0 | reads a1(8) | q1 | lgkmcnt(0)+barrier (buf p free)
//   | stage A of kt+2 -> buf p | q2 | stage B | q3 | vmcnt(8)+barrier (kt+1 landed)
// vmcnt never drains to 0 in-loop (T4); setprio around MFMA quadrants (T5).
template <int FMAP, int OUT>
__global__ __launch_bounds__(512, 2) void gemm256(
    const unsigned short* __restrict__ A, const unsigned short* __restrict__ W,
    const float* __restrict__ bias, void* __restrict__ Cout) {
  __shared__ short lds[65536];                    // [2 buf][A 16384 | B 16384]
  const int bid = blockIdx.x;                     // 512 blocks
  const int swz = (bid & 7) * 64 + (bid >> 3);    // XCD-chunked (512%8==0)
  const int mt = swz >> 2;                        // 0..127
  const int nt = swz & 3;                         // 0..3

  const int tid = threadIdx.x;
  const int lane = tid & 63;
  const int w = tid >> 6;
  const int wr = w >> 2, wc = w & 3;
  const int l15 = lane & 15, lh = lane >> 4;

  const int arow0 = mt * 256, brow0 = nt * 256;

  // stage one matrix K-tile: 2048 x 16B chunks, 4 per thread, linear LDS dest
  auto stage = [&](const unsigned short* __restrict__ src, int lbase, int rowbase, int k0) {
#pragma unroll
    for (int i = 0; i < 4; ++i) {
      const int c = i * 512 + tid;
      const int r = c >> 3, ps = c & 7;
      const int sg = ps ^ (r & 7);                 // inverse swizzle on source
      load_lds16(src + (rowbase + r) * KDIM + k0 + sg * 8, &lds[lbase + c * 8]);
    }
  };

  f32x4_t acc[8][4];
#pragma unroll
  for (int m = 0; m < 8; ++m)
#pragma unroll
    for (int n = 0; n < 4; ++n) acc[m][n] = (f32x4_t)0.0f;

  // prologue: stage kt0 -> buf0, kt1 -> buf1
  stage(A, 0, arow0, 0);
  stage(W, 16384, brow0, 0);
  stage(A, 32768, arow0, 64);
  stage(W, 49152, brow0, 64);
  asm volatile("s_waitcnt vmcnt(8)" ::: "memory");   // kt0 (oldest 8) landed
  __builtin_amdgcn_sched_barrier(0);
  __builtin_amdgcn_s_barrier();

  s16x8_t a0[4][2], a1[4][2], bf[4][2];

  auto rdA = [&](int pb, int m, int ks) -> s16x8_t {
    const int row = wr * 128 + m * 16 + l15;
    const int off = pb + row * 64 + (((ks * 4 + lh) ^ (row & 7)) * 8);
    return *reinterpret_cast<const s16x8_t*>(&lds[off]);
  };
  auto rdB = [&](int pb, int n, int ks) -> s16x8_t {
    const int row = wc * 64 + n * 16 + l15;
    const int off = pb + 16384 + row * 64 + (((ks * 4 + lh) ^ (row & 7)) * 8);
    return *reinterpret_cast<const s16x8_t*>(&lds[off]);
  };
  auto quad = [&](s16x8_t (&af)[4][2], int mbase, int nlo) {
    __builtin_amdgcn_s_setprio(1);
#pragma unroll
    for (int m = 0; m < 4; ++m)
#pragma unroll
      for (int n = 0; n < 2; ++n)
#pragma unroll
        for (int ks = 0; ks < 2; ++ks)
          acc[mbase + m][nlo + n] = __builtin_amdgcn_mfma_f32_16x16x32_bf16(
              __builtin_bit_cast(bf16x8_t, af[m][ks]),
              __builtin_bit_cast(bf16x8_t, bf[nlo + n][ks]),
              acc[mbase + m][nlo + n], 0, 0, 0);
    __builtin_amdgcn_s_setprio(0);
  };

  for (int kt = 0; kt < 16; ++kt) {
    const int pb = (kt & 1) * 32768;
#pragma unroll
    for (int m = 0; m < 4; ++m)
#pragma unroll
      for (int ks = 0; ks < 2; ++ks) a0[m][ks] = rdA(pb, m, ks);
#pragma unroll
    for (int n = 0; n < 4; ++n)
#pragma unroll
      for (int ks = 0; ks < 2; ++ks) bf[n][ks] = rdB(pb, n, ks);
    quad(a0, 0, 0);                                 // q0 (compiler waits on deps)
#pragma unroll
    for (int m = 0; m < 4; ++m)
#pragma unroll
      for (int ks = 0; ks < 2; ++ks) a1[m][ks] = rdA(pb, m + 4, ks);
    quad(a0, 0, 2);                                 // q1
    __builtin_amdgcn_sched_barrier(0);
    asm volatile("s_waitcnt lgkmcnt(0)" ::: "memory");  // all reads of buf p done
    __builtin_amdgcn_sched_barrier(0);
    __builtin_amdgcn_s_barrier();                   // -> buf p free for overwrite
    const int k2 = ((kt + 2) & 15) * 64;            // wrapped: uniform code, junk tail ok
    stage(A, pb, arow0, k2);
    quad(a1, 4, 0);                                 // q2
    stage(W, pb + 16384, brow0, k2);
    quad(a1, 4, 2);                                 // q3
    if (kt < 15) {
      __builtin_amdgcn_sched_barrier(0);
      asm volatile("s_waitcnt vmcnt(8)" ::: "memory");  // kt+1 landed; kt+2's 8 in flight
      __builtin_amdgcn_sched_barrier(0);
      __builtin_amdgcn_s_barrier();
    }
  }

  // epilogue: C/D layout col = lane&15, row = (lane>>4)*4 + j  [m89/m91]
#pragma unroll
  for (int n = 0; n < 4; ++n) {
    const int col = nt * 256 + wc * 64 + n * 16 + l15;
    const float bv = bias[col];
#pragma unroll
    for (int m = 0; m < 8; ++m) {
      const int row0 = mt * 256 + wr * 128 + m * 16 + lh * 4;
      if (OUT == 2) {
        const int b = row0 >> 13, tl = row0 & 8191;
        const int h = col >> 6, d = col & 63;
        s16x4_t o;
#pragma unroll
        for (int j = 0; j < 4; ++j) {
          float v = acc[m][n][j] + bv;
          if (FMAP) v = (v > 0.0f) ? (v + 1.0f) : __expf(v);
          o[j] = (short)f2bf_bits(v);
        }
        *reinterpret_cast<s16x4_t*>(
            reinterpret_cast<unsigned short*>(Cout) +
            (((b * 16 + h) * 64 + d) * 8192 + tl)) = o;
      } else {
#pragma unroll
        for (int j = 0; j < 4; ++j) {
          float v = acc[m][n][j] + bv;
          if (FMAP) v = (v > 0.0f) ? (v + 1.0f) : __expf(v);  // elu(x)+1
          if (OUT == 1)
            reinterpret_cast<float*>(Cout)[(row0 + j) * NDIM + col] = v;
          else
            reinterpret_cast<unsigned short*>(Cout)[(row0 + j) * NDIM + col] = f2bf_bits(v);
        }
      }
    }
  }
}

// ---------------------------------------------------------------- kv + k_sum (MFMA, streaming)
// Inputs transposed: kT[bh][d][8192 t], vT[bh][e][8192 t] (bf16).
__global__ __launch_bounds__(256) void kv_ksum_mfma(
    const unsigned short* __restrict__ kT, const unsigned short* __restrict__ vT,
    float* __restrict__ kvT, float* __restrict__ ksum) {
  const int bid = blockIdx.x;
  const int bh = bid >> 4, ch = bid & 15;
  const int tid = threadIdx.x;
  const int lane = tid & 63, w = tid >> 6;
  const int l15 = lane & 15, lh = lane >> 4;
  const int dblk = (w >> 1) * 32, eblk = (w & 1) * 32;

  f32x4_t acc[2][2];
#pragma unroll
  for (int m = 0; m < 2; ++m)
#pragma unroll
    for (int n = 0; n < 2; ++n) acc[m][n] = (f32x4_t)0.0f;
  float ks0 = 0.f, ks1 = 0.f;

  const int tbase = ch * 512 + lh * 8;
  const unsigned short* ka = kT + (bh * 64 + dblk + l15) * 8192 + tbase;
  const unsigned short* va = vT + (bh * 64 + eblk + l15) * 8192 + tbase;

  for (int t0 = 0; t0 < 512; t0 += 32) {
    s16x8_t ar[2], br[2];
#pragma unroll
    for (int m = 0; m < 2; ++m)
      ar[m] = *reinterpret_cast<const s16x8_t*>(ka + m * 16 * 8192 + t0);
#pragma unroll
    for (int n = 0; n < 2; ++n)
      br[n] = *reinterpret_cast<const s16x8_t*>(va + n * 16 * 8192 + t0);
#pragma unroll
    for (int m = 0; m < 2; ++m)
#pragma unroll
      for (int n = 0; n < 2; ++n)
        acc[m][n] = __builtin_amdgcn_mfma_f32_16x16x32_bf16(
            __builtin_bit_cast(bf16x8_t, ar[m]),
            __builtin_bit_cast(bf16x8_t, br[n]), acc[m][n], 0, 0, 0);
    if (eblk == 0) {
#pragma unroll
      for (int i = 0; i < 8; ++i) ks0 += bf2f((unsigned short)ar[0][i]);
#pragma unroll
      for (int i = 0; i < 8; ++i) ks1 += bf2f((unsigned short)ar[1][i]);
    }
  }

  if (eblk == 0) {
    ks0 += __shfl_xor(ks0, 16); ks0 += __shfl_xor(ks0, 32);
    ks1 += __shfl_xor(ks1, 16); ks1 += __shfl_xor(ks1, 32);
    if (lh == 0) {
      atomicAdd(&ksum[bh * 64 + dblk + l15], ks0);
      atomicAdd(&ksum[bh * 64 + dblk + 16 + l15], ks1);
    }
  }
#pragma unroll
  for (int n = 0; n < 2; ++n) {
    const int e = eblk + n * 16 + l15;
#pragma unroll
    for (int m = 0; m < 2; ++m) {
      const int d0 = dblk + m * 16 + lh * 4;
#pragma unroll
      for (int j = 0; j < 4; ++j)
        atomicAdd(&kvT[(bh * 64 + e) * 64 + d0 + j], acc[m][n][j]);
    }
  }
}

// ---------------------------------------------------------------- out = q@kv / (q.ksum+eps)
__global__ __launch_bounds__(256) void attn_apply_kernel(
    const unsigned short* __restrict__ qf, const float* __restrict__ kvT,
    const float* __restrict__ ksum, unsigned short* __restrict__ att) {
  const int bid = blockIdx.x;                     // 2048
  const int swz = (bid & 7) * 256 + (bid >> 3);
  const int bh = swz >> 5;
  const int tile = swz & 31;
  const int b = bh >> 4, h = bh & 15;
  const int tid = threadIdx.x;
  const int lane = tid & 63, w = tid >> 6;
  const int l15 = lane & 15, lh = lane >> 4;

  float ksr[16];
#pragma unroll
  for (int i = 0; i < 16; ++i) ksr[i] = ksum[bh * 64 + lh * 16 + i];

  bf16x8_t bfrag[2][4];
#pragma unroll
  for (int ks2 = 0; ks2 < 2; ++ks2)
#pragma unroll
    for (int n = 0; n < 4; ++n) {
      const float* p = kvT + (bh * 64 + n * 16 + l15) * 64 + ks2 * 32 + lh * 8;
      f32x4_t p0 = *reinterpret_cast<const f32x4_t*>(p);
      f32x4_t p1 = *reinterpret_cast<const f32x4_t*>(p + 4);
      s16x8_t t;
      t[0] = (short)f2bf_bits(p0[0]); t[1] = (short)f2bf_bits(p0[1]);
      t[2] = (short)f2bf_bits(p0[2]); t[3] = (short)f2bf_bits(p0[3]);
      t[4] = (short)f2bf_bits(p1[0]); t[5] = (short)f2bf_bits(p1[1]);
      t[6] = (short)f2bf_bits(p1[2]); t[7] = (short)f2bf_bits(p1[3]);
      bfrag[ks2][n] = __builtin_bit_cast(bf16x8_t, t);
    }

  const int rbase = b * 8192 + tile * 256 + w * 64;
  f32x4_t acc[4][4];
#pragma unroll
  for (int m = 0; m < 4; ++m)
#pragma unroll
    for (int n = 0; n < 4; ++n) acc[m][n] = (f32x4_t)0.0f;
  float rden[4][4];

#pragma unroll
  for (int m = 0; m < 4; ++m) {
    const int row = rbase + m * 16 + l15;
    const unsigned short* qrow = qf + row * 1024 + h * 64;
    bf16x8_t afr[2];
#pragma unroll
    for (int ks2 = 0; ks2 < 2; ++ks2)
      afr[ks2] = __builtin_bit_cast(bf16x8_t,
          *reinterpret_cast<const s16x8_t*>(qrow + ks2 * 32 + lh * 8));
    s16x8_t qa = *reinterpret_cast<const s16x8_t*>(qrow + lh * 16);
    s16x8_t qb = *reinterpret_cast<const s16x8_t*>(qrow + lh * 16 + 8);
    float part = 0.f;
#pragma unroll
    for (int i = 0; i < 8; ++i) part += bf2f((unsigned short)qa[i]) * ksr[i];
#pragma unroll
    for (int i = 0; i < 8; ++i) part += bf2f((unsigned short)qb[i]) * ksr[8 + i];
    part += __shfl_xor(part, 16);
    part += __shfl_xor(part, 32);
#pragma unroll
    for (int j = 0; j < 4; ++j) {
      float dj = __shfl(part, lh * 4 + j);
      rden[m][j] = 1.0f / (dj + EPSV);
    }
#pragma unroll
    for (int ks2 = 0; ks2 < 2; ++ks2)
#pragma unroll
      for (int n = 0; n < 4; ++n)
        acc[m][n] = __builtin_amdgcn_mfma_f32_16x16x32_bf16(afr[ks2], bfrag[ks2][n], acc[m][n], 0, 0, 0);
  }

#pragma unroll
  for (int m = 0; m < 4; ++m)
#pragma unroll
    for (int n = 0; n < 4; ++n) {
      const int col = h * 64 + n * 16 + l15;
#pragma unroll
      for (int j = 0; j < 4; ++j) {
        const int row = rbase + m * 16 + lh * 4 + j;
        att[row * 1024 + col] = f2bf_bits(acc[m][n][j] * rden[m][j]);
      }
    }
}

// ---------------------------------------------------------------- launch
extern "C" void kernel_launch(void* const* d_in, const int* in_sizes, int n_in,
                              void* d_out, int out_size, void* d_ws, size_t ws_size,
                              hipStream_t stream) {
  const float* query = (const float*)d_in[0];
  const float* key   = (const float*)d_in[1];
  const float* value = (const float*)d_in[2];
  const float* Wq = (const float*)d_in[3];
  const float* bq = (const float*)d_in[4];
  const float* Wk = (const float*)d_in[5];
  const float* bk = (const float*)d_in[6];
  const float* Wv = (const float*)d_in[7];
  const float* bv = (const float*)d_in[8];
  const float* Wo = (const float*)d_in[9];
  const float* bo = (const float*)d_in[10];
  float* out = (float*)d_out;

  if (ws_size < 277889024ULL) return;
  char* ws = (char*)d_ws;
  unsigned short* Vbf = (unsigned short*)(ws + 0);          // value bf16; reused as att
  unsigned short* qf  = (unsigned short*)(ws + 67108864);
  unsigned short* kTf = (unsigned short*)(ws + 134217728);  // k transposed [b][h][d][t]
  unsigned short* vTf = (unsigned short*)(ws + 201326592);  // v transposed
  unsigned short* Wqb = (unsigned short*)(ws + 268435456);
  unsigned short* Wkb = Wqb + 1048576;
  unsigned short* Wvb = Wkb + 1048576;
  unsigned short* Wob = Wvb + 1048576;
  float* kvT  = (float*)(ws + 276824064);
  float* ksum = (float*)(ws + 277872640);

  unsigned short* Qbf = (unsigned short*)d_out;   // d_out doubles as bf16 scratch
  unsigned short* Kbf = Qbf + 33554432;

  hipMemsetAsync(kvT, 0, (size_t)(64 * 64 * 64 + 64 * 64) * sizeof(float), stream);

  convert_f32_bf16<<<2048, 256, 0, stream>>>(query, Qbf, 33554432LL);
  convert_f32_bf16<<<2048, 256, 0, stream>>>(key,   Kbf, 33554432LL);
  convert_f32_bf16<<<2048, 256, 0, stream>>>(value, Vbf, 33554432LL);
  convert_f32_bf16<<<512, 256, 0, stream>>>(Wq, Wqb, 1048576LL);
  convert_f32_bf16<<<512, 256, 0, stream>>>(Wk, Wkb, 1048576LL);
  convert_f32_bf16<<<512, 256, 0, stream>>>(Wv, Wvb, 1048576LL);
  convert_f32_bf16<<<512, 256, 0, stream>>>(Wo, Wob, 1048576LL);

  gemm256<1, 0><<<512, 512, 0, stream>>>(Qbf, Wqb, bq, qf);   // q row-major
  gemm256<1, 2><<<512, 512, 0, stream>>>(Kbf, Wkb, bk, kTf);  // k transposed
  gemm256<0, 2><<<512, 512, 0, stream>>>(Vbf, Wvb, bv, vTf);  // v transposed

  kv_ksum_mfma<<<1024, 256, 0, stream>>>(kTf, vTf, kvT, ksum);

  attn_apply_kernel<<<2048, 256, 0, stream>>>(qf, kvT, ksum, Vbf);  // att -> Vbf

  gemm256<0, 1><<<512, 512, 0, stream>>>(Vbf, Wob, bo, out);  // final -> f32
}